// Round 10
// baseline (62011.182 us; speedup 1.0000x reference)
//
#include <hip/hip_runtime.h>
#include <math.h>

#define NBLK 256
#define NTHR 512

#define BB    64
#define TIN   512
#define EEE   512
#define TOUTT 800
#define NMEL  80
#define PPP   256
#define ALS   1024
#define DLS   1024
#define ATTD  128
#define KA    1792
#define KD    2560

typedef _Float16 f16;
typedef f16 f16x8 __attribute__((ext_vector_type(8)));
typedef f16 f16x2 __attribute__((ext_vector_type(2)));
typedef float f32x4 __attribute__((ext_vector_type(4)));
typedef unsigned long long u64;

// ---- ws carve (float units) ----
#define WTA_OFF   0ull          // f16[4096*1792]
#define WTD_OFF   3670016ull    // f16[4096*2560]
#define PM16_OFF  8912896ull    // f16[64*512*128]
#define ENC16_OFF 11010048ull   // f16[64*512*512]
#define PRE_OFF   19398656ull   // f16[800*16384]
#define XA_OFF    25952256ull   // f16[2*114688]
#define XD_OFF    26066944ull   // f16[2*163840]
#define AH16_OFF  26230784ull   // f16[64*1024]
#define DH16_OFF  26263552ull   // f16[64*1024]
#define CTX16_OFF 26296320ull   // f16[2*64*512]
#define EN_OFF    26329088ull   // reused: f16[8192] KW B-frags (kwb)
#define WQT_OFF   26361856ull   // f16[128*1024]
#define WPJT_OFF  26427392ull   // f16[81*1536]
#define WP1T_OFF  26489600ull   // f16[256*80]
#define WP2T_OFF  26499840ull   // f16[256*256]
#define WLP_OFF   26532608ull   // u32[128*16] (unused by loop now)
#define KLP_OFF   26534656ull   // u32[31*32]  (unused by loop now)
#define BAR_OFF   26535648ull   // 272 u32

// smem f32 regions
#define PL_O   0     // 512
#define RED_O  512   // 16
#define QL_O   528   // 136
#define PART_O 664   // 1024

__device__ __forceinline__ float sigm(float x) { return 1.0f / (1.0f + __expf(-x)); }
// overflow-safe fast tanh
__device__ __forceinline__ float ftanh(float x) {
  return 1.f - 2.f / (__expf(2.f * x) + 1.f);
}

union pk32 { unsigned u; f16x2 h; float f; };
__device__ __forceinline__ unsigned packh2(float a, float b) {
  pk32 p; p.h[0] = (f16)a; p.h[1] = (f16)b; return p.u;
}

// agent-scope (sc1, L2-bypass) accessors: ALL mutable cross-block data uses these
__device__ __forceinline__ u64 ld64cg(const void* p) {
  return __hip_atomic_load((const u64*)p, __ATOMIC_RELAXED, __HIP_MEMORY_SCOPE_AGENT);
}
__device__ __forceinline__ void stu16cg(void* p, unsigned short v) {
  __hip_atomic_store((unsigned short*)p, v, __ATOMIC_RELAXED, __HIP_MEMORY_SCOPE_AGENT);
}
__device__ __forceinline__ void stu32cg(void* p, unsigned v) {
  __hip_atomic_store((unsigned*)p, v, __ATOMIC_RELAXED, __HIP_MEMORY_SCOPE_AGENT);
}
// 16B sc1 vector load as two u64 atomics (proven correct in R8/R9)
__device__ __forceinline__ f16x8 ld128cg(const f16* p) {
  union { u64 q[2]; f16x8 v; } r;
  r.q[0] = ld64cg(p);
  r.q[1] = ld64cg(p + 4);
  return r.v;
}

// fragment-order address (f16 units): A-frag for 16x16x32
__device__ __forceinline__ size_t fragaddr(int b, int k) {
  return (size_t)(k >> 5) * 2048 + (size_t)(b >> 4) * 512 +
         (size_t)(((b & 15) + (((k & 31) >> 3) << 4)) << 3) + (k & 7);
}

// ---- grid barrier: full=true only in prologue; loop barriers fence-free ----
__device__ __forceinline__ void gbar(unsigned* bar, unsigned& n, bool full) {
  n += 1;
  __syncthreads();   // vmcnt(0) drain: all sc1 stores ack'd at coherence point
  if (threadIdx.x == 0) {
    if (full) __threadfence();
    __hip_atomic_fetch_add(&bar[(blockIdx.x & 15) << 4], 1u, __ATOMIC_RELAXED, __HIP_MEMORY_SCOPE_AGENT);
  }
  if (threadIdx.x < 64) {
    const unsigned tgt = n * 16u;
    const unsigned g = (threadIdx.x & 15) << 4;
    asm volatile("" ::: "memory");
    while (!__all((threadIdx.x >= 16) ||
                  (__hip_atomic_load(&bar[g], __ATOMIC_RELAXED, __HIP_MEMORY_SCOPE_AGENT) >= tgt)))
      __builtin_amdgcn_s_sleep(1);
    asm volatile("" ::: "memory");
    if (full) __threadfence();
  }
  __syncthreads();
}

// ---- weight transpose + f16: Wt[col][k] ----
__global__ void __launch_bounds__(256) transA(const float* __restrict__ Wi,
                                              const float* __restrict__ Wh,
                                              f16* __restrict__ Wt) {
  __shared__ float tile[64][65];
  const int tid = threadIdx.x;
  const int kb = (int)blockIdx.x % 28;
  const int cb = (int)blockIdx.x / 28;
  const int k0 = kb * 64, c0 = cb * 64;
  for (int i = tid; i < 4096; i += 256) {
    const int r = i >> 6, c = i & 63;
    const int k = k0 + r;
    const float v = (k < 768) ? Wi[(size_t)k * 4096 + c0 + c]
                              : Wh[(size_t)(k - 768) * 4096 + c0 + c];
    tile[c][r] = v;
  }
  __syncthreads();
  for (int i = tid; i < 4096; i += 256) {
    const int c = i >> 6, kk = i & 63;
    Wt[(size_t)(c0 + c) * KA + k0 + kk] = (f16)tile[c][kk];
  }
}

__global__ void __launch_bounds__(256) transD(const float* __restrict__ Wi,
                                              const float* __restrict__ Wh,
                                              f16* __restrict__ Wt) {
  __shared__ float tile[64][65];
  const int tid = threadIdx.x;
  const int kb = (int)blockIdx.x % 40;
  const int cb = (int)blockIdx.x / 40;
  const int k0 = kb * 64, c0 = cb * 64;
  for (int i = tid; i < 4096; i += 256) {
    const int r = i >> 6, c = i & 63;
    const int k = k0 + r;
    const float v = (k < 1536) ? Wi[(size_t)k * 4096 + c0 + c]
                               : Wh[(size_t)(k - 1536) * 4096 + c0 + c];
    tile[c][r] = v;
  }
  __syncthreads();
  for (int i = tid; i < 4096; i += 256) {
    const int c = i >> 6, kk = i & 63;
    Wt[(size_t)(c0 + c) * KD + k0 + kk] = (f16)tile[c][kk];
  }
}

// ---- pm = enc @ Wm -> f16 ----
__global__ void __launch_bounds__(128) pmk(const float* __restrict__ enc,
                                           const float* __restrict__ Wm,
                                           f16* __restrict__ pm16) {
  __shared__ float er[512];
  const int tid = threadIdx.x;
  const int b = (int)blockIdx.x >> 9, tt = (int)blockIdx.x & 511;
  for (int i = tid; i < 512; i += 128) er[i] = enc[((size_t)b * TIN + tt) * EEE + i];
  __syncthreads();
  float s = 0.f;
  #pragma unroll 4
  for (int k = 0; k < 512; ++k) s += er[k] * Wm[k * ATTD + tid];
  pm16[((size_t)b * TIN + tt) * ATTD + tid] = (f16)s;
}

// ---- enc -> f16 ----
__global__ void __launch_bounds__(512) enc16k(const float* __restrict__ enc,
                                              f16* __restrict__ e16) {
  const size_t i = ((size_t)blockIdx.x * 512 + threadIdx.x) * 8;
  const float4 v0 = *reinterpret_cast<const float4*>(enc + i);
  const float4 v1 = *reinterpret_cast<const float4*>(enc + i + 4);
  f16x8 o;
  o[0] = (f16)v0.x; o[1] = (f16)v0.y; o[2] = (f16)v0.z; o[3] = (f16)v0.w;
  o[4] = (f16)v1.x; o[5] = (f16)v1.y; o[6] = (f16)v1.z; o[7] = (f16)v1.w;
  *reinterpret_cast<f16x8*>(e16 + i) = o;
}

// ---- KW = fold(Kloc, Wloc): KW[2k+c][a] = sum_f Kloc[f,c,k]*Wloc[f,a], B-frag order ----
__global__ void __launch_bounds__(256) kwk(const float* __restrict__ Kloc,
                                           const float* __restrict__ Wloc,
                                           f16* __restrict__ kwb) {
  const int idx = (int)blockIdx.x * 256 + (int)threadIdx.x;  // 8192 = 64 kc * 128 a
  const int kc = idx >> 7, a = idx & 127;
  const int k = kc >> 1, cch = kc & 1;
  float s = 0.f;
  if (k < 31) {
    #pragma unroll 8
    for (int f = 0; f < 32; ++f)
      s += Kloc[f * 62 + cch * 31 + k] * Wloc[f * 128 + a];
  }
  // B-frag position: tile ct=a>>4, col n=a&15; ks=kc>>5, lane-hi=(kc&31)>>3, j=kc&7
  const int ct = a >> 4, n = a & 15;
  const int ks = kc >> 5, kcl = kc & 31, kch = kcl >> 3, j = kcl & 7;
  kwb[((size_t)(ct * 2 + ks) * 64 + (kch * 16 + n)) * 8 + j] = (f16)s;
}

// ---- aux transposes / packs ----
__global__ void __launch_bounds__(512) transAux(const float* __restrict__ Wq,
                                                const float* __restrict__ Wproj,
                                                const float* __restrict__ Wgate,
                                                const float* __restrict__ Wp1,
                                                const float* __restrict__ Wp2,
                                                f16* __restrict__ wqt,
                                                f16* __restrict__ wpjt,
                                                f16* __restrict__ wp1t,
                                                f16* __restrict__ wp2t) {
  const int idx = (int)blockIdx.x * 512 + (int)threadIdx.x;
  if (idx < 131072) {
    const int a = idx >> 10, k = idx & 1023;
    wqt[idx] = (f16)Wq[k * 128 + a];
  } else if (idx < 131072 + 124416) {
    const int j = idx - 131072;
    const int m = j / 1536, k = j % 1536;
    wpjt[j] = (f16)(m < 80 ? Wproj[k * 80 + m] : Wgate[k]);
  } else if (idx < 131072 + 124416 + 20480) {
    const int j = idx - (131072 + 124416);
    const int col = j / 80, k = j % 80;
    wp1t[j] = (f16)Wp1[k * 256 + col];
  } else if (idx < 131072 + 124416 + 20480 + 65536) {
    const int j = idx - (131072 + 124416 + 20480);
    const int col = j >> 8, k = j & 255;
    wp2t[j] = (f16)Wp2[k * 256 + col];
  }
}

// ---- prenet precompute -> fragment layout ----
__global__ void __launch_bounds__(512) prenetk(const float* __restrict__ dec_in,
                                               const f16* __restrict__ wp1t,
                                               const f16* __restrict__ wp2t,
                                               f16* __restrict__ pre) {
  __shared__ float xl[64 * 80];
  __shared__ f16 h1l[64 * 264];
  const int t = (int)blockIdx.x;
  const int tid = threadIdx.x;
  f16* out = pre + (size_t)t * 16384;
  if (t == 0) {
    unsigned* o32 = (unsigned*)out;
    for (int i = tid; i < 8192; i += 512) o32[i] = 0u;
    return;
  }
  for (int i = tid; i < 5120; i += 512) {
    const int b = i / 80, m = i % 80;
    xl[b * 80 + m] = dec_in[(size_t)b * (NMEL * TOUTT) + (size_t)m * TOUTT + (t - 1)];
  }
  __syncthreads();
  {
    const int col = tid & 255, bh = tid >> 8;
    for (int bb = 0; bb < 32; ++bb) {
      const int b = bh * 32 + bb;
      float s = 0.f;
      #pragma unroll 4
      for (int k = 0; k < 80; ++k) s += xl[b * 80 + k] * (float)wp1t[col * 80 + k];
      h1l[b * 264 + col] = (f16)fmaxf(s, 0.f);
    }
  }
  __syncthreads();
  {
    const int col = tid & 255, bh = tid >> 8;
    for (int bb = 0; bb < 32; ++bb) {
      const int b = bh * 32 + bb;
      float s = 0.f;
      #pragma unroll 4
      for (int k = 0; k < 256; ++k) s += (float)h1l[b * 264 + k] * (float)wp2t[col * 256 + k];
      out[fragaddr(b, col)] = (f16)fmaxf(s, 0.f);
    }
  }
}

// ---- LSTM epilogue: C-reduce + cell nonlinearity; state in registers; sc1 writes ----
__device__ __forceinline__ void lstm_tail(int bid, int tid, float* smemf,
                                          const f32x4 c, int kh, int mt, int lane,
                                          const float* __restrict__ bias, float& creg,
                                          f16* __restrict__ h16,
                                          f16* frag1, int k1off,
                                          f16* frag2, int k2off) {
  float* Call = smemf;
  float* CallB = smemf + 1024;
  const int r0 = mt * 16 + (lane >> 4) * 4;
  const int n = lane & 15;
  if (kh == 1) {
    #pragma unroll
    for (int j = 0; j < 4; ++j) CallB[(r0 + j) * 16 + n] = c[j];
  }
  __syncthreads();
  if (kh == 0) {
    #pragma unroll
    for (int j = 0; j < 4; ++j) Call[(r0 + j) * 16 + n] = c[j] + CallB[(r0 + j) * 16 + n];
  }
  __syncthreads();
  if (tid < 256) {
    const int b = tid & 63, q = tid >> 6;
    const int cc = bid * 4 + q;
    const float g0 = Call[b * 16 + q]      + bias[cc];
    const float g1 = Call[b * 16 + 4 + q]  + bias[1024 + cc];
    const float g2 = Call[b * 16 + 8 + q]  + bias[2048 + cc];
    const float g3 = Call[b * 16 + 12 + q] + bias[3072 + cc];
    const float cn = sigm(g1) * creg + sigm(g0) * ftanh(g2);
    creg = cn;
    const float h = sigm(g3) * ftanh(cn);
    pk32 hp; hp.h[0] = (f16)h; hp.h[1] = (f16)0.f;
    const unsigned short hu = (unsigned short)(hp.u & 0xFFFFu);
    stu16cg(h16 + (size_t)b * 1024 + cc, hu);
    if (frag1) stu16cg(frag1 + fragaddr(b, k1off + cc), hu);
    if (frag2) stu16cg(frag2 + fragaddr(b, k2off + cc), hu);
  }
}

// ---- mel/gate projection with LDS staging (256+128 u64) ----
__device__ __forceinline__ void do_melgate(int b, int half, int tcol,
                                           const f16* __restrict__ dh16,
                                           const f16* __restrict__ ctx16p,
                                           const f16* __restrict__ wpjt,
                                           const float* __restrict__ bproj,
                                           const float* __restrict__ bgate,
                                           float* __restrict__ out_mel,
                                           float* __restrict__ out_gate,
                                           float* smem) {
  const int tid = threadIdx.x;
  __syncthreads();  // protect smem reuse
  u64* dhl = (u64*)smem;          // 256 u64 -> smem[0..512)
  u64* ctl = (u64*)smem + 256;    // 128 u64 -> smem[512..768)
  if (tid < 256)      dhl[tid] = ld64cg((const u64*)(dh16 + (size_t)b * 1024) + tid);
  else if (tid < 384) ctl[tid - 256] = ld64cg((const u64*)(ctx16p + (size_t)b * 512) + (tid - 256));
  __syncthreads();
  float* melp = smem + 768;       // 492 floats
  const int nrow = half ? 40 : 41;
  const int ml = tid / 12, kq = tid % 12;
  if (ml < nrow) {
    const int m = half * 41 + ml;
    const f16* wr = wpjt + (size_t)m * 1536 + kq * 128;
    const f16* xl = (kq < 8) ? ((const f16*)dhl + kq * 128)
                             : ((const f16*)ctl + (kq - 8) * 128);
    float s = 0.f;
    #pragma unroll
    for (int c8 = 0; c8 < 16; ++c8) {
      const f16x8 xv = *reinterpret_cast<const f16x8*>(xl + c8 * 8);
      const f16x8 wv = *reinterpret_cast<const f16x8*>(wr + c8 * 8);
      #pragma unroll
      for (int j = 0; j < 8; ++j) s += (float)xv[j] * (float)wv[j];
    }
    melp[ml * 12 + kq] = s;
  }
  __syncthreads();
  if (tid < nrow) {
    float s = 0.f;
    #pragma unroll
    for (int j = 0; j < 12; ++j) s += melp[tid * 12 + j];
    const int m = half * 41 + tid;
    if (m < 80) out_mel[(size_t)b * NMEL * TOUTT + (size_t)m * TOUTT + tcol] = s + bproj[m];
    else        out_gate[(size_t)b * TOUTT + tcol] = s + bgate[0];
  }
}

__global__ void __launch_bounds__(NTHR, 1)
decoder_loop(const int* __restrict__ tlen,
             const float* __restrict__ b_a, const float* __restrict__ b_d,
             const float* __restrict__ Wv,
             const float* __restrict__ bproj, const float* __restrict__ bgate,
             const f16* __restrict__ wta_h, const f16* __restrict__ wtd_h,
             const f16* __restrict__ pm16, const f16* __restrict__ enc16,
             const f16* __restrict__ pre_h,
             const f16* __restrict__ wqt, const f16* __restrict__ wpjt,
             const f16* __restrict__ kwb,
             f16* __restrict__ xa_h, f16* __restrict__ xd_h,
             f16* __restrict__ ah16, f16* __restrict__ dh16,
             f16* __restrict__ ctx16,
             unsigned* bar,
             float* __restrict__ out_mel, float* __restrict__ out_gate,
             float* __restrict__ out_align) {
  __shared__ f16 wfA[28672];      // 57,344 B
  __shared__ f16 wfD[40960];      // 81,920 B
  __shared__ float smem[2048];    // 8,192 B
  __shared__ unsigned awb[544];   // (aw,awc) f16 pairs + guards

  const int tid = threadIdx.x;
  const int bid = (int)blockIdx.x;
  const int lane = tid & 63;
  const int w = tid >> 6;
  const int mt = w & 3, kh = w >> 2;
  const int b = bid & 63;
  const int chn = bid >> 6;
  unsigned syncn = 0;

  // ---- prologue: pack B-fragments into LDS ----
  for (int i = tid; i < 3584; i += NTHR) {
    const int ks = i >> 6, l = i & 63;
    const int n = l & 15, kc = (l >> 4) * 8;
    const int gcol = (n >> 2) * 1024 + bid * 4 + (n & 3);
    const uint4 v = *reinterpret_cast<const uint4*>(wta_h + (size_t)gcol * KA + ks * 32 + kc);
    *reinterpret_cast<uint4*>(&wfA[(size_t)i * 8]) = v;
  }
  for (int i = tid; i < 5120; i += NTHR) {
    const int ks = i >> 6, l = i & 63;
    const int n = l & 15, kc = (l >> 4) * 8;
    const int gcol = (n >> 2) * 1024 + bid * 4 + (n & 3);
    const uint4 v = *reinterpret_cast<const uint4*>(wtd_h + (size_t)gcol * KD + ks * 32 + kc);
    *reinterpret_cast<uint4*>(&wfD[(size_t)i * 8]) = v;
  }
  for (int i = tid; i < 544; i += NTHR) awb[i] = 0u;
  {
    unsigned* za = (unsigned*)xa_h;   // xa+xd contiguous: 278,528 u32
    const int gid = bid * NTHR + tid;
    for (int i = gid; i < 278528; i += NBLK * NTHR) za[i] = 0u;
  }
  gbar(bar, syncn, true);   // the ONLY full-fence barrier

  const int len = tlen[b];
  float awcf = 0.f;
  float cregA = 0.f, cregD = 0.f;

  for (int t = 0; t <= TOUTT; ++t) {
    // ========== X: decoder LSTM (t-1), attention LSTM (t) ==========
    if (t > 0) {
      const f16* xdP = xd_h + (size_t)((t - 1) & 1) * 163840;
      const f16* abase = xdP + (size_t)(kh * 40) * 2048 + mt * 512 + lane * 8;
      const f16* bbase = wfD + ((size_t)(kh * 40) * 64 + lane) * 8;
      f32x4 c = {0.f, 0.f, 0.f, 0.f};
      #pragma unroll 8
      for (int ks = 0; ks < 40; ++ks) {
        const f16x8 af = ld128cg(abase + (size_t)ks * 2048);
        const f16x8 bf = *reinterpret_cast<const f16x8*>(bbase + (size_t)ks * 512);
        c = __builtin_amdgcn_mfma_f32_16x16x32_f16(af, bf, c, 0, 0, 0);
      }
      lstm_tail(bid, tid, smem, c, kh, mt, lane, b_d, cregD, dh16,
                xd_h + (size_t)(t & 1) * 163840, 1536, (f16*)0, 0);
    }
    if (t < TOUTT) {
      const f16* xaP = xa_h + (size_t)(t & 1) * 114688;
      const f16* preP = pre_h + (size_t)t * 16384;
      const f16* bbase = wfA + ((size_t)(kh * 28) * 64 + lane) * 8;
      f32x4 c = {0.f, 0.f, 0.f, 0.f};
      #pragma unroll 8
      for (int ks = 0; ks < 28; ++ks) {
        const int kg = kh * 28 + ks;
        const f16* ap = (kg < 8) ? preP : xaP;
        const f16x8 af = (kg < 8)
            ? *reinterpret_cast<const f16x8*>(ap + (size_t)kg * 2048 + mt * 512 + lane * 8)
            : ld128cg(ap + (size_t)kg * 2048 + mt * 512 + lane * 8);
        const f16x8 bf = *reinterpret_cast<const f16x8*>(bbase + (size_t)ks * 512);
        c = __builtin_amdgcn_mfma_f32_16x16x32_f16(af, bf, c, 0, 0, 0);
      }
      lstm_tail(bid, tid, smem, c, kh, mt, lane, b_a, cregA, ah16,
                xa_h + (size_t)((t + 1) & 1) * 114688, 768,
                xd_h + (size_t)(t & 1) * 163840, 0);
    }
    gbar(bar, syncn, false);  // B1

    if (t == TOUTT) {
      if (chn == 1 || chn == 2)
        do_melgate(b, chn - 1, TOUTT - 1, dh16, ctx16 + (size_t)((TOUTT - 1) & 1) * 32768,
                   wpjt, bproj, bgate, out_mel, out_gate, smem);
      break;
    }

    // ========== Y: q + KW-GEMM energies + softmax + ctx quarter + melgate ==========
    {
      // stage ah16 row b -> LDS (full 1024 f16)
      u64* ahl = (u64*)smem;   // smem[0..512)
      if (tid < 256) ahl[tid] = ld64cg((const u64*)(ah16 + (size_t)b * 1024) + tid);
      __syncthreads();
      // q partials  (wqt: plain loads, L2-resident forever — no fences in loop)
      {
        const int a = tid & 127, kq = tid >> 7;
        const f16* arow = (const f16*)ahl + kq * 256;
        const f16* wr = wqt + (size_t)a * 1024 + kq * 256;
        float s = 0.f;
        #pragma unroll 8
        for (int c8 = 0; c8 < 32; ++c8) {
          const f16x8 xv = *reinterpret_cast<const f16x8*>(arow + c8 * 8);
          const f16x8 wv = *reinterpret_cast<const f16x8*>(wr + c8 * 8);
          #pragma unroll
          for (int j = 0; j < 8; ++j) s += (float)xv[j] * (float)wv[j];
        }
        smem[PART_O + kq * 128 + a] = s;
      }
      __syncthreads();
      if (tid < 128) {
        const int a = tid;
        smem[QL_O + a + (a >> 5)] = smem[PART_O + a] + smem[PART_O + 128 + a] +
                                    smem[PART_O + 256 + a] + smem[PART_O + 384 + a];
      }
      __syncthreads();

      // hoist this lane's 8 (ql, Wv) values (a = ct*16 + lane&15)
      float qlv[8], wvv[8];
      #pragma unroll
      for (int ct = 0; ct < 8; ++ct) {
        const int a = ct * 16 + (lane & 15);
        qlv[ct] = smem[QL_O + a + (a >> 5)];
        wvv[ct] = Wv[a];
      }

      // (conv ∘ Wloc) as ONE GEMM: ploc[r][a] = im2col(awb) @ KW.
      // A-frags read DIRECTLY from awb (pairs are interleaved (aw,awc) = K-order).
      // Each wave: 4 row-tiles (rows w*64 .. w*64+63).
      for (int rt4 = 0; rt4 < 4; ++rt4) {
        const int rt = w * 4 + rt4;
        const int r_a = rt * 16 + (lane & 15);       // A-row for this lane
        f32x4 c[8];
        #pragma unroll
        for (int ct = 0; ct < 8; ++ct) c[ct] = (f32x4){0.f, 0.f, 0.f, 0.f};
        #pragma unroll
        for (int ks = 0; ks < 2; ++ks) {
          const int tap = (lane >> 4) * 4 + ks * 16;
          union { unsigned u[4]; f16x8 v; } af;
          #pragma unroll
          for (int q4 = 0; q4 < 4; ++q4) af.u[q4] = awb[1 + r_a + tap + q4];
          #pragma unroll
          for (int ct = 0; ct < 8; ++ct) {
            const f16x8 bf = *reinterpret_cast<const f16x8*>(
                kwb + ((size_t)(ct * 2 + ks) * 64 + lane) * 8);
            c[ct] = __builtin_amdgcn_mfma_f32_16x16x32_f16(af.v, bf, c[ct], 0, 0, 0);
          }
        }
        // consume: e-partials for rows rt*16 + (lane>>4)*4 + j
        float ep[4] = {0.f, 0.f, 0.f, 0.f};
        #pragma unroll
        for (int ct = 0; ct < 8; ++ct) {
          const int a = ct * 16 + (lane & 15);
          #pragma unroll
          for (int j = 0; j < 4; ++j) {
            const int r = rt * 16 + ((lane >> 4) << 2) + j;
            const float pmv = (float)pm16[(size_t)(b * TIN + r) * ATTD + a];
            ep[j] += wvv[ct] * ftanh(qlv[ct] + c[ct][j] + pmv);
          }
        }
        #pragma unroll
        for (int j = 0; j < 4; ++j) {
          ep[j] += __shfl_xor(ep[j], 1);
          ep[j] += __shfl_xor(ep[j], 2);
          ep[j] += __shfl_xor(ep[j], 4);
          ep[j] += __shfl_xor(ep[j], 8);
        }
        if ((lane & 15) == 0) {
          #pragma unroll
          for (int j = 0; j < 4; ++j)
            smem[PL_O + rt * 16 + ((lane >> 4) << 2) + j] = ep[j];
        }
      }

      // softmax (own-row read: same wave wrote it)
      const float ee = (tid < len) ? smem[PL_O + tid] : -1e30f;
      float m = ee;
      #pragma unroll
      for (int o = 32; o > 0; o >>= 1) m = fmaxf(m, __shfl_xor(m, o));
      if (lane == 0) smem[RED_O + w] = m;
      __syncthreads();
      if (tid == 0) {
        float mm = smem[RED_O];
        #pragma unroll
        for (int i = 1; i < 8; ++i) mm = fmaxf(mm, smem[RED_O + i]);
        smem[RED_O + 8] = mm;
      }
      __syncthreads();
      const float M = smem[RED_O + 8];
      const float p = (tid < len) ? __expf(ee - M) : 0.f;
      float s = p;
      #pragma unroll
      for (int o = 32; o > 0; o >>= 1) s += __shfl_xor(s, o);
      if (lane == 0) smem[RED_O + w] = s;
      __syncthreads();
      if (tid == 0) {
        float ss = smem[RED_O];
        #pragma unroll
        for (int i = 1; i < 8; ++i) ss += smem[RED_O + i];
        smem[RED_O + 8] = ss;
      }
      __syncthreads();
      const float an = p * (1.f / smem[RED_O + 8]);
      smem[PL_O + tid] = an;
      awcf += an;
      awb[16 + tid] = packh2(an, awcf);
      if (chn == 0) out_align[((size_t)b * TOUTT + t) * TIN + tid] = an;
      __syncthreads();

      // ctx e-quarter (enc16 via nontemporal loads: no L2 pollution)
      {
        const int eo = lane & 15, sub4 = lane >> 4;
        float a8[8];
        #pragma unroll
        for (int i = 0; i < 8; ++i) a8[i] = 0.f;
        const f16* ebase = enc16 + (size_t)(b * TIN) * EEE + chn * 128 + eo * 8;
        #pragma unroll 4
        for (int j = 0; j < 16; ++j) {
          const int tj = w * 64 + sub4 * 16 + j;
          const float wv = smem[PL_O + tj];
          const f16x8 ev = __builtin_nontemporal_load(
              reinterpret_cast<const f16x8*>(ebase + (size_t)tj * EEE));
          #pragma unroll
          for (int i = 0; i < 8; ++i) a8[i] += wv * (float)ev[i];
        }
        #pragma unroll
        for (int i = 0; i < 8; ++i) {
          a8[i] += __shfl_xor(a8[i], 16);
          a8[i] += __shfl_xor(a8[i], 32);
        }
        if (lane < 16) {
          #pragma unroll
          for (int i = 0; i < 8; ++i) smem[PART_O + w * 128 + eo * 8 + i] = a8[i];
        }
      }
      __syncthreads();
      if (tid < 128) {
        float v = 0.f;
        #pragma unroll
        for (int ww = 0; ww < 8; ++ww) v += smem[PART_O + ww * 128 + tid];
        smem[PL_O + tid] = v;
      }
      __syncthreads();
      if (tid < 64) {
        const int ecol = chn * 128 + 2 * tid;
        const unsigned pv = packh2(smem[PL_O + 2 * tid], smem[PL_O + 2 * tid + 1]);
        stu32cg((unsigned*)(xa_h + (size_t)((t + 1) & 1) * 114688 + fragaddr(b, 256 + ecol)), pv);
        stu32cg((unsigned*)(xd_h + (size_t)(t & 1) * 163840 + fragaddr(b, 1024 + ecol)), pv);
        stu32cg((unsigned*)(ctx16 + (size_t)(t & 1) * 32768 + (size_t)b * 512 + ecol), pv);
      }
      if (t > 0 && (chn == 1 || chn == 2))
        do_melgate(b, chn - 1, t - 1, dh16, ctx16 + (size_t)((t - 1) & 1) * 32768,
                   wpjt, bproj, bgate, out_mel, out_gate, smem);
    }
    gbar(bar, syncn, false);  // B2
  }
}

extern "C" void kernel_launch(void* const* d_in, const int* in_sizes, int n_in,
                              void* d_out, int out_size, void* d_ws, size_t ws_size,
                              hipStream_t stream) {
  (void)in_sizes; (void)n_in; (void)out_size; (void)ws_size;
  const float* enc    = (const float*)d_in[0];
  const float* dec_in = (const float*)d_in[1];
  const int*   tlen   = (const int*)d_in[2];
  const float* Wp1    = (const float*)d_in[3];
  const float* Wp2    = (const float*)d_in[4];
  const float* Wi_a   = (const float*)d_in[5];
  const float* Wh_a   = (const float*)d_in[6];
  const float* b_a    = (const float*)d_in[7];
  const float* Wq     = (const float*)d_in[8];
  const float* Wm     = (const float*)d_in[9];
  const float* Wv     = (const float*)d_in[10];
  const float* Kloc   = (const float*)d_in[11];
  const float* Wloc   = (const float*)d_in[12];
  const float* Wi_d   = (const float*)d_in[13];
  const float* Wh_d   = (const float*)d_in[14];
  const float* b_d    = (const float*)d_in[15];
  const float* Wproj  = (const float*)d_in[16];
  const float* bproj  = (const float*)d_in[17];
  const float* Wgate  = (const float*)d_in[18];
  const float* bgate  = (const float*)d_in[19];

  float* ws = (float*)d_ws;
  f16*   wta_h = (f16*)(ws + WTA_OFF);
  f16*   wtd_h = (f16*)(ws + WTD_OFF);
  f16*   pm16  = (f16*)(ws + PM16_OFF);
  f16*   e16   = (f16*)(ws + ENC16_OFF);
  f16*   pre_h = (f16*)(ws + PRE_OFF);
  f16*   xa_h  = (f16*)(ws + XA_OFF);
  f16*   xd_h  = (f16*)(ws + XD_OFF);
  f16*   ah16  = (f16*)(ws + AH16_OFF);
  f16*   dh16  = (f16*)(ws + DH16_OFF);
  f16*   ctx16 = (f16*)(ws + CTX16_OFF);
  f16*   kwb   = (f16*)(ws + EN_OFF);     // reuse dead EN region for KW B-frags
  f16*   wqt   = (f16*)(ws + WQT_OFF);
  f16*   wpjt  = (f16*)(ws + WPJT_OFF);
  f16*   wp1t  = (f16*)(ws + WP1T_OFF);
  f16*   wp2t  = (f16*)(ws + WP2T_OFF);
  unsigned* bar = (unsigned*)(ws + BAR_OFF);

  float* out_mel   = (float*)d_out;
  float* out_gate  = out_mel + (size_t)BB * NMEL * TOUTT;
  float* out_align = out_gate + (size_t)BB * TOUTT;

  hipMemsetAsync(bar, 0, 272 * sizeof(unsigned), stream);
  transA<<<dim3(28 * 64), dim3(256), 0, stream>>>(Wi_a, Wh_a, wta_h);
  transD<<<dim3(40 * 64), dim3(256), 0, stream>>>(Wi_d, Wh_d, wtd_h);
  pmk<<<dim3(BB * TIN), dim3(128), 0, stream>>>(enc, Wm, pm16);
  enc16k<<<dim3(4096), dim3(512), 0, stream>>>(enc, e16);
  kwk<<<dim3(32), dim3(256), 0, stream>>>(Kloc, Wloc, kwb);
  transAux<<<dim3(667), dim3(512), 0, stream>>>(Wq, Wproj, Wgate, Wp1, Wp2,
                                                wqt, wpjt, wp1t, wp2t);
  prenetk<<<dim3(TOUTT), dim3(512), 0, stream>>>(dec_in, wp1t, wp2t, pre_h);
  decoder_loop<<<dim3(NBLK), dim3(NTHR), 0, stream>>>(
      tlen, b_a, b_d, Wv, bproj, bgate,
      wta_h, wtd_h, pm16, e16, pre_h, wqt, wpjt, kwb,
      xa_h, xd_h, ah16, dh16, ctx16, bar,
      out_mel, out_gate, out_align);
}

// Round 11
// 56452.618 us; speedup vs baseline: 1.0985x; 1.0985x over previous
//
#include <hip/hip_runtime.h>
#include <math.h>

#define NBLK 256
#define NTHR 512

#define BB    64
#define TIN   512
#define EEE   512
#define TOUTT 800
#define NMEL  80
#define PPP   256
#define ALS   1024
#define DLS   1024
#define ATTD  128
#define KA    1792
#define KD    2560

typedef _Float16 f16;
typedef f16 f16x8 __attribute__((ext_vector_type(8)));
typedef f16 f16x2 __attribute__((ext_vector_type(2)));
typedef float f32x4 __attribute__((ext_vector_type(4)));
typedef unsigned long long u64;

// ---- ws carve (float units) ----
#define WTA_OFF   0ull          // f16[4096*1792]
#define WTD_OFF   3670016ull    // f16[4096*2560]
#define PM16_OFF  8912896ull    // f16[64*512*128]
#define ENC16_OFF 11010048ull   // f16[64*512*512]
#define PRE_OFF   19398656ull   // f16[800*16384]
#define XA_OFF    25952256ull   // f16[2*114688]
#define XD_OFF    26066944ull   // f16[2*163840]
#define AH16_OFF  26230784ull   // f16[64*1024]
#define DH16_OFF  26263552ull   // f16[64*1024]
#define CTX16_OFF 26296320ull   // f16[2*64*512]
#define EN_OFF    26329088ull   // reused: f16[8192] KW B-frags (kwb)
#define WQT_OFF   26361856ull   // f16[128*1024]
#define WPJT_OFF  26427392ull   // f16[81*1536]
#define WP1T_OFF  26489600ull   // f16[256*80]
#define WP2T_OFF  26499840ull   // f16[256*256]
#define BAR_OFF   26535648ull   // 272 u32

// smem f32 regions
#define PL_O   0     // 512
#define RED_O  512   // 16
#define QL_O   528   // 136
#define PART_O 664   // 1024

__device__ __forceinline__ float sigm(float x) { return 1.0f / (1.0f + __expf(-x)); }
// overflow-safe fast tanh
__device__ __forceinline__ float ftanh(float x) {
  return 1.f - 2.f / (__expf(2.f * x) + 1.f);
}

union pk32 { unsigned u; f16x2 h; float f; };
__device__ __forceinline__ unsigned packh2(float a, float b) {
  pk32 p; p.h[0] = (f16)a; p.h[1] = (f16)b; return p.u;
}

// agent-scope (sc1, L2-bypass) accessors for mutable cross-block data
__device__ __forceinline__ u64 ld64cg(const void* p) {
  return __hip_atomic_load((const u64*)p, __ATOMIC_RELAXED, __HIP_MEMORY_SCOPE_AGENT);
}
__device__ __forceinline__ void stf32cg(void* p, float v) {
  __hip_atomic_store((float*)p, v, __ATOMIC_RELAXED, __HIP_MEMORY_SCOPE_AGENT);
}
__device__ __forceinline__ void stu16cg(void* p, unsigned short v) {
  __hip_atomic_store((unsigned short*)p, v, __ATOMIC_RELAXED, __HIP_MEMORY_SCOPE_AGENT);
}
__device__ __forceinline__ void stu32cg(void* p, unsigned v) {
  __hip_atomic_store((unsigned*)p, v, __ATOMIC_RELAXED, __HIP_MEMORY_SCOPE_AGENT);
}

// fragment-order address (f16 units): A-frag for 16x16x32
__device__ __forceinline__ size_t fragaddr(int b, int k) {
  return (size_t)(k >> 5) * 2048 + (size_t)(b >> 4) * 512 +
         (size_t)(((b & 15) + (((k & 31) >> 3) << 4)) << 3) + (k & 7);
}

// ---- grid barrier. mode: 0=fence-free, 1=full (wb+inv, prologue only),
//      2=acquire-invalidate (buffer_inv; producers are sc1 write-through so no wb needed)
__device__ __forceinline__ void gbar(unsigned* bar, unsigned& n, int mode) {
  n += 1;
  __syncthreads();   // vmcnt(0) drain: all sc1 stores ack'd at L3 before flag add
  if (threadIdx.x == 0) {
    if (mode == 1) __threadfence();
    __hip_atomic_fetch_add(&bar[(blockIdx.x & 15) << 4], 1u, __ATOMIC_RELAXED, __HIP_MEMORY_SCOPE_AGENT);
  }
  if (threadIdx.x < 64) {
    const unsigned tgt = n * 16u;
    const unsigned g = (threadIdx.x & 15) << 4;
    asm volatile("" ::: "memory");
    while (!__all((threadIdx.x >= 16) ||
                  (__hip_atomic_load(&bar[g], __ATOMIC_RELAXED, __HIP_MEMORY_SCOPE_AGENT) >= tgt)))
      __builtin_amdgcn_s_sleep(1);
    asm volatile("" ::: "memory");
    if (mode == 1) __threadfence();
    else if (mode == 2) __builtin_amdgcn_fence(__ATOMIC_ACQUIRE, "agent");  // L1+L2 inv, no wb
  }
  __syncthreads();
}

// ---- weight transpose + f16: Wt[col][k] ----
__global__ void __launch_bounds__(256) transA(const float* __restrict__ Wi,
                                              const float* __restrict__ Wh,
                                              f16* __restrict__ Wt) {
  __shared__ float tile[64][65];
  const int tid = threadIdx.x;
  const int kb = (int)blockIdx.x % 28;
  const int cb = (int)blockIdx.x / 28;
  const int k0 = kb * 64, c0 = cb * 64;
  for (int i = tid; i < 4096; i += 256) {
    const int r = i >> 6, c = i & 63;
    const int k = k0 + r;
    const float v = (k < 768) ? Wi[(size_t)k * 4096 + c0 + c]
                              : Wh[(size_t)(k - 768) * 4096 + c0 + c];
    tile[c][r] = v;
  }
  __syncthreads();
  for (int i = tid; i < 4096; i += 256) {
    const int c = i >> 6, kk = i & 63;
    Wt[(size_t)(c0 + c) * KA + k0 + kk] = (f16)tile[c][kk];
  }
}

__global__ void __launch_bounds__(256) transD(const float* __restrict__ Wi,
                                              const float* __restrict__ Wh,
                                              f16* __restrict__ Wt) {
  __shared__ float tile[64][65];
  const int tid = threadIdx.x;
  const int kb = (int)blockIdx.x % 40;
  const int cb = (int)blockIdx.x / 40;
  const int k0 = kb * 64, c0 = cb * 64;
  for (int i = tid; i < 4096; i += 256) {
    const int r = i >> 6, c = i & 63;
    const int k = k0 + r;
    const float v = (k < 1536) ? Wi[(size_t)k * 4096 + c0 + c]
                               : Wh[(size_t)(k - 1536) * 4096 + c0 + c];
    tile[c][r] = v;
  }
  __syncthreads();
  for (int i = tid; i < 4096; i += 256) {
    const int c = i >> 6, kk = i & 63;
    Wt[(size_t)(c0 + c) * KD + k0 + kk] = (f16)tile[c][kk];
  }
}

// ---- pm = enc @ Wm -> f16 ----
__global__ void __launch_bounds__(128) pmk(const float* __restrict__ enc,
                                           const float* __restrict__ Wm,
                                           f16* __restrict__ pm16) {
  __shared__ float er[512];
  const int tid = threadIdx.x;
  const int b = (int)blockIdx.x >> 9, tt = (int)blockIdx.x & 511;
  for (int i = tid; i < 512; i += 128) er[i] = enc[((size_t)b * TIN + tt) * EEE + i];
  __syncthreads();
  float s = 0.f;
  #pragma unroll 4
  for (int k = 0; k < 512; ++k) s += er[k] * Wm[k * ATTD + tid];
  pm16[((size_t)b * TIN + tt) * ATTD + tid] = (f16)s;
}

// ---- enc -> f16 ----
__global__ void __launch_bounds__(512) enc16k(const float* __restrict__ enc,
                                              f16* __restrict__ e16) {
  const size_t i = ((size_t)blockIdx.x * 512 + threadIdx.x) * 8;
  const float4 v0 = *reinterpret_cast<const float4*>(enc + i);
  const float4 v1 = *reinterpret_cast<const float4*>(enc + i + 4);
  f16x8 o;
  o[0] = (f16)v0.x; o[1] = (f16)v0.y; o[2] = (f16)v0.z; o[3] = (f16)v0.w;
  o[4] = (f16)v1.x; o[5] = (f16)v1.y; o[6] = (f16)v1.z; o[7] = (f16)v1.w;
  *reinterpret_cast<f16x8*>(e16 + i) = o;
}

// ---- KW = fold(Kloc, Wloc): KW[2k+c][a] = sum_f Kloc[f,c,k]*Wloc[f,a], B-frag order ----
__global__ void __launch_bounds__(256) kwk(const float* __restrict__ Kloc,
                                           const float* __restrict__ Wloc,
                                           f16* __restrict__ kwb) {
  const int idx = (int)blockIdx.x * 256 + (int)threadIdx.x;  // 8192 = 64 kc * 128 a
  const int kc = idx >> 7, a = idx & 127;
  const int k = kc >> 1, cch = kc & 1;
  float s = 0.f;
  if (k < 31) {
    #pragma unroll 8
    for (int f = 0; f < 32; ++f)
      s += Kloc[f * 62 + cch * 31 + k] * Wloc[f * 128 + a];
  }
  const int ct = a >> 4, n = a & 15;
  const int ks = kc >> 5, kcl = kc & 31, kch = kcl >> 3, j = kcl & 7;
  kwb[((size_t)(ct * 2 + ks) * 64 + (kch * 16 + n)) * 8 + j] = (f16)s;
}

// ---- aux transposes / packs ----
__global__ void __launch_bounds__(512) transAux(const float* __restrict__ Wq,
                                                const float* __restrict__ Wproj,
                                                const float* __restrict__ Wgate,
                                                const float* __restrict__ Wp1,
                                                const float* __restrict__ Wp2,
                                                f16* __restrict__ wqt,
                                                f16* __restrict__ wpjt,
                                                f16* __restrict__ wp1t,
                                                f16* __restrict__ wp2t) {
  const int idx = (int)blockIdx.x * 512 + (int)threadIdx.x;
  if (idx < 131072) {
    const int a = idx >> 10, k = idx & 1023;
    wqt[idx] = (f16)Wq[k * 128 + a];
  } else if (idx < 131072 + 124416) {
    const int j = idx - 131072;
    const int m = j / 1536, k = j % 1536;
    wpjt[j] = (f16)(m < 80 ? Wproj[k * 80 + m] : Wgate[k]);
  } else if (idx < 131072 + 124416 + 20480) {
    const int j = idx - (131072 + 124416);
    const int col = j / 80, k = j % 80;
    wp1t[j] = (f16)Wp1[k * 256 + col];
  } else if (idx < 131072 + 124416 + 20480 + 65536) {
    const int j = idx - (131072 + 124416 + 20480);
    const int col = j >> 8, k = j & 255;
    wp2t[j] = (f16)Wp2[k * 256 + col];
  }
}

// ---- prenet precompute -> fragment layout ----
__global__ void __launch_bounds__(512) prenetk(const float* __restrict__ dec_in,
                                               const f16* __restrict__ wp1t,
                                               const f16* __restrict__ wp2t,
                                               f16* __restrict__ pre) {
  __shared__ float xl[64 * 80];
  __shared__ f16 h1l[64 * 264];
  const int t = (int)blockIdx.x;
  const int tid = threadIdx.x;
  f16* out = pre + (size_t)t * 16384;
  if (t == 0) {
    unsigned* o32 = (unsigned*)out;
    for (int i = tid; i < 8192; i += 512) o32[i] = 0u;
    return;
  }
  for (int i = tid; i < 5120; i += 512) {
    const int b = i / 80, m = i % 80;
    xl[b * 80 + m] = dec_in[(size_t)b * (NMEL * TOUTT) + (size_t)m * TOUTT + (t - 1)];
  }
  __syncthreads();
  {
    const int col = tid & 255, bh = tid >> 8;
    for (int bb = 0; bb < 32; ++bb) {
      const int b = bh * 32 + bb;
      float s = 0.f;
      #pragma unroll 4
      for (int k = 0; k < 80; ++k) s += xl[b * 80 + k] * (float)wp1t[col * 80 + k];
      h1l[b * 264 + col] = (f16)fmaxf(s, 0.f);
    }
  }
  __syncthreads();
  {
    const int col = tid & 255, bh = tid >> 8;
    for (int bb = 0; bb < 32; ++bb) {
      const int b = bh * 32 + bb;
      float s = 0.f;
      #pragma unroll 4
      for (int k = 0; k < 256; ++k) s += (float)h1l[b * 264 + k] * (float)wp2t[col * 256 + k];
      out[fragaddr(b, col)] = (f16)fmaxf(s, 0.f);
    }
  }
}

// ---- LSTM epilogue: C-reduce + cell nonlinearity; state in registers; sc1 writes ----
__device__ __forceinline__ void lstm_tail(int bid, int tid, float* smemf,
                                          const f32x4 c, int kh, int mt, int lane,
                                          const float* __restrict__ bias, float& creg,
                                          f16* __restrict__ h16,
                                          f16* frag1, int k1off,
                                          f16* frag2, int k2off) {
  float* Call = smemf;
  float* CallB = smemf + 1024;
  const int r0 = mt * 16 + (lane >> 4) * 4;
  const int n = lane & 15;
  if (kh == 1) {
    #pragma unroll
    for (int j = 0; j < 4; ++j) CallB[(r0 + j) * 16 + n] = c[j];
  }
  __syncthreads();
  if (kh == 0) {
    #pragma unroll
    for (int j = 0; j < 4; ++j) Call[(r0 + j) * 16 + n] = c[j] + CallB[(r0 + j) * 16 + n];
  }
  __syncthreads();
  if (tid < 256) {
    const int b = tid & 63, q = tid >> 6;
    const int cc = bid * 4 + q;
    const float g0 = Call[b * 16 + q]      + bias[cc];
    const float g1 = Call[b * 16 + 4 + q]  + bias[1024 + cc];
    const float g2 = Call[b * 16 + 8 + q]  + bias[2048 + cc];
    const float g3 = Call[b * 16 + 12 + q] + bias[3072 + cc];
    const float cn = sigm(g1) * creg + sigm(g0) * ftanh(g2);
    creg = cn;
    const float h = sigm(g3) * ftanh(cn);
    pk32 hp; hp.h[0] = (f16)h; hp.h[1] = (f16)0.f;
    const unsigned short hu = (unsigned short)(hp.u & 0xFFFFu);
    stu16cg(h16 + (size_t)b * 1024 + cc, hu);
    if (frag1) stu16cg(frag1 + fragaddr(b, k1off + cc), hu);
    if (frag2) stu16cg(frag2 + fragaddr(b, k2off + cc), hu);
  }
}

// ---- mel/gate projection with LDS staging (256+128 u64); sc1 outputs ----
__device__ __forceinline__ void do_melgate(int b, int half, int tcol,
                                           const f16* __restrict__ dh16,
                                           const f16* __restrict__ ctx16p,
                                           const f16* __restrict__ wpjt,
                                           const float* __restrict__ bproj,
                                           const float* __restrict__ bgate,
                                           float* __restrict__ out_mel,
                                           float* __restrict__ out_gate,
                                           float* smem) {
  const int tid = threadIdx.x;
  __syncthreads();  // protect smem reuse
  u64* dhl = (u64*)smem;          // 256 u64 -> smem[0..512)
  u64* ctl = (u64*)smem + 256;    // 128 u64 -> smem[512..768)
  if (tid < 256)      dhl[tid] = ld64cg((const u64*)(dh16 + (size_t)b * 1024) + tid);
  else if (tid < 384) ctl[tid - 256] = ld64cg((const u64*)(ctx16p + (size_t)b * 512) + (tid - 256));
  __syncthreads();
  float* melp = smem + 768;       // 492 floats
  const int nrow = half ? 40 : 41;
  const int ml = tid / 12, kq = tid % 12;
  if (ml < nrow) {
    const int m = half * 41 + ml;
    const f16* wr = wpjt + (size_t)m * 1536 + kq * 128;
    const f16* xl = (kq < 8) ? ((const f16*)dhl + kq * 128)
                             : ((const f16*)ctl + (kq - 8) * 128);
    float s = 0.f;
    #pragma unroll
    for (int c8 = 0; c8 < 16; ++c8) {
      const f16x8 xv = *reinterpret_cast<const f16x8*>(xl + c8 * 8);
      const f16x8 wv = *reinterpret_cast<const f16x8*>(wr + c8 * 8);
      #pragma unroll
      for (int j = 0; j < 8; ++j) s += (float)xv[j] * (float)wv[j];
    }
    melp[ml * 12 + kq] = s;
  }
  __syncthreads();
  if (tid < nrow) {
    float s = 0.f;
    #pragma unroll
    for (int j = 0; j < 12; ++j) s += melp[tid * 12 + j];
    const int m = half * 41 + tid;
    if (m < 80) stf32cg(out_mel + (size_t)b * NMEL * TOUTT + (size_t)m * TOUTT + tcol, s + bproj[m]);
    else        stf32cg(out_gate + (size_t)b * TOUTT + tcol, s + bgate[0]);
  }
}

__global__ void __launch_bounds__(NTHR, 1)
decoder_loop(const int* __restrict__ tlen,
             const float* __restrict__ b_a, const float* __restrict__ b_d,
             const float* __restrict__ Wv,
             const float* __restrict__ bproj, const float* __restrict__ bgate,
             const f16* __restrict__ wta_h, const f16* __restrict__ wtd_h,
             const f16* __restrict__ pm16, const f16* __restrict__ enc16,
             const f16* __restrict__ pre_h,
             const f16* __restrict__ wqt, const f16* __restrict__ wpjt,
             const f16* __restrict__ kwb,
             f16* __restrict__ xa_h, f16* __restrict__ xd_h,
             f16* __restrict__ ah16, f16* __restrict__ dh16,
             f16* __restrict__ ctx16,
             unsigned* bar,
             float* __restrict__ out_mel, float* __restrict__ out_gate,
             float* __restrict__ out_align) {
  __shared__ f16 wfA[28672];      // 57,344 B
  __shared__ f16 wfD[40960];      // 81,920 B
  __shared__ float smem[2048];    // 8,192 B
  __shared__ unsigned awb[544];   // (aw,awc) f16 pairs + guards

  const int tid = threadIdx.x;
  const int bid = (int)blockIdx.x;
  const int lane = tid & 63;
  const int w = tid >> 6;
  const int mt = w & 3, kh = w >> 2;
  const int b = bid & 63;
  const int chn = bid >> 6;
  unsigned syncn = 0;

  // ---- prologue: pack B-fragments into LDS ----
  for (int i = tid; i < 3584; i += NTHR) {
    const int ks = i >> 6, l = i & 63;
    const int n = l & 15, kc = (l >> 4) * 8;
    const int gcol = (n >> 2) * 1024 + bid * 4 + (n & 3);
    const uint4 v = *reinterpret_cast<const uint4*>(wta_h + (size_t)gcol * KA + ks * 32 + kc);
    *reinterpret_cast<uint4*>(&wfA[(size_t)i * 8]) = v;
  }
  for (int i = tid; i < 5120; i += NTHR) {
    const int ks = i >> 6, l = i & 63;
    const int n = l & 15, kc = (l >> 4) * 8;
    const int gcol = (n >> 2) * 1024 + bid * 4 + (n & 3);
    const uint4 v = *reinterpret_cast<const uint4*>(wtd_h + (size_t)gcol * KD + ks * 32 + kc);
    *reinterpret_cast<uint4*>(&wfD[(size_t)i * 8]) = v;
  }
  for (int i = tid; i < 544; i += NTHR) awb[i] = 0u;
  {
    unsigned* za = (unsigned*)xa_h;   // xa+xd contiguous: 278,528 u32
    const int gid = bid * NTHR + tid;
    for (int i = gid; i < 278528; i += NBLK * NTHR) za[i] = 0u;
  }
  gbar(bar, syncn, 1);   // full fence (prologue only)

  const int len = tlen[b];
  float awcf = 0.f;
  float cregA = 0.f, cregD = 0.f;

  for (int t = 0; t <= TOUTT; ++t) {
    // ========== X: decoder LSTM (t-1), attention LSTM (t) ==========
    // A-frags: PLAIN cached b128 loads (lines are clean L3 copies after B2's inv;
    // 32 blocks/XCD share them through L2)
    if (t > 0) {
      const f16* xdP = xd_h + (size_t)((t - 1) & 1) * 163840;
      const f16* abase = xdP + (size_t)(kh * 40) * 2048 + mt * 512 + lane * 8;
      const f16* bbase = wfD + ((size_t)(kh * 40) * 64 + lane) * 8;
      f32x4 c = {0.f, 0.f, 0.f, 0.f};
      #pragma unroll 8
      for (int ks = 0; ks < 40; ++ks) {
        const f16x8 af = *reinterpret_cast<const f16x8*>(abase + (size_t)ks * 2048);
        const f16x8 bf = *reinterpret_cast<const f16x8*>(bbase + (size_t)ks * 512);
        c = __builtin_amdgcn_mfma_f32_16x16x32_f16(af, bf, c, 0, 0, 0);
      }
      lstm_tail(bid, tid, smem, c, kh, mt, lane, b_d, cregD, dh16,
                xd_h + (size_t)(t & 1) * 163840, 1536, (f16*)0, 0);
    }
    if (t < TOUTT) {
      const f16* xaP = xa_h + (size_t)(t & 1) * 114688;
      const f16* preP = pre_h + (size_t)t * 16384;
      const f16* bbase = wfA + ((size_t)(kh * 28) * 64 + lane) * 8;
      f32x4 c = {0.f, 0.f, 0.f, 0.f};
      #pragma unroll 8
      for (int ks = 0; ks < 28; ++ks) {
        const int kg = kh * 28 + ks;
        const f16* ap = (kg < 8) ? preP : xaP;
        const f16x8 af = *reinterpret_cast<const f16x8*>(ap + (size_t)kg * 2048 + mt * 512 + lane * 8);
        const f16x8 bf = *reinterpret_cast<const f16x8*>(bbase + (size_t)ks * 512);
        c = __builtin_amdgcn_mfma_f32_16x16x32_f16(af, bf, c, 0, 0, 0);
      }
      lstm_tail(bid, tid, smem, c, kh, mt, lane, b_a, cregA, ah16,
                xa_h + (size_t)((t + 1) & 1) * 114688, 768,
                xd_h + (size_t)(t & 1) * 163840, 0);
    }
    gbar(bar, syncn, 0);  // B1 (fence-free; Y reads ah16 via sc1)

    if (t == TOUTT) {
      if (chn == 1 || chn == 2)
        do_melgate(b, chn - 1, TOUTT - 1, dh16, ctx16 + (size_t)((TOUTT - 1) & 1) * 32768,
                   wpjt, bproj, bgate, out_mel, out_gate, smem);
      break;
    }

    // ========== Y: q + KW-GEMM energies + softmax + ctx quarter + melgate ==========
    {
      // stage ah16 row b -> LDS (full 1024 f16)
      u64* ahl = (u64*)smem;   // smem[0..512)
      if (tid < 256) ahl[tid] = ld64cg((const u64*)(ah16 + (size_t)b * 1024) + tid);
      __syncthreads();
      // q partials
      {
        const int a = tid & 127, kq = tid >> 7;
        const f16* arow = (const f16*)ahl + kq * 256;
        const f16* wr = wqt + (size_t)a * 1024 + kq * 256;
        float s = 0.f;
        #pragma unroll 8
        for (int c8 = 0; c8 < 32; ++c8) {
          const f16x8 xv = *reinterpret_cast<const f16x8*>(arow + c8 * 8);
          const f16x8 wv = *reinterpret_cast<const f16x8*>(wr + c8 * 8);
          #pragma unroll
          for (int j = 0; j < 8; ++j) s += (float)xv[j] * (float)wv[j];
        }
        smem[PART_O + kq * 128 + a] = s;
      }
      __syncthreads();
      if (tid < 128) {
        const int a = tid;
        smem[QL_O + a + (a >> 5)] = smem[PART_O + a] + smem[PART_O + 128 + a] +
                                    smem[PART_O + 256 + a] + smem[PART_O + 384 + a];
      }
      __syncthreads();

      // hoist this lane's 8 (ql, Wv) values (a = ct*16 + lane&15)
      float qlv[8], wvv[8];
      #pragma unroll
      for (int ct = 0; ct < 8; ++ct) {
        const int a = ct * 16 + (lane & 15);
        qlv[ct] = smem[QL_O + a + (a >> 5)];
        wvv[ct] = Wv[a];
      }

      // (conv ∘ Wloc) as ONE GEMM: ploc[r][a] = im2col(awb) @ KW
      for (int rt4 = 0; rt4 < 4; ++rt4) {
        const int rt = w * 4 + rt4;
        const int r_a = rt * 16 + (lane & 15);       // A-row for this lane
        f32x4 c[8];
        #pragma unroll
        for (int ct = 0; ct < 8; ++ct) c[ct] = (f32x4){0.f, 0.f, 0.f, 0.f};
        #pragma unroll
        for (int ks = 0; ks < 2; ++ks) {
          const int tap = (lane >> 4) * 4 + ks * 16;
          union { unsigned u[4]; f16x8 v; } af;
          #pragma unroll
          for (int q4 = 0; q4 < 4; ++q4) af.u[q4] = awb[1 + r_a + tap + q4];
          #pragma unroll
          for (int ct = 0; ct < 8; ++ct) {
            const f16x8 bf = *reinterpret_cast<const f16x8*>(
                kwb + ((size_t)(ct * 2 + ks) * 64 + lane) * 8);
            c[ct] = __builtin_amdgcn_mfma_f32_16x16x32_f16(af.v, bf, c[ct], 0, 0, 0);
          }
        }
        // consume: e-partials for rows rt*16 + (lane>>4)*4 + j
        float ep[4] = {0.f, 0.f, 0.f, 0.f};
        #pragma unroll
        for (int ct = 0; ct < 8; ++ct) {
          const int a = ct * 16 + (lane & 15);
          #pragma unroll
          for (int j = 0; j < 4; ++j) {
            const int r = rt * 16 + ((lane >> 4) << 2) + j;
            const float pmv = (float)pm16[(size_t)(b * TIN + r) * ATTD + a];
            ep[j] += wvv[ct] * ftanh(qlv[ct] + c[ct][j] + pmv);
          }
        }
        #pragma unroll
        for (int j = 0; j < 4; ++j) {
          ep[j] += __shfl_xor(ep[j], 1);
          ep[j] += __shfl_xor(ep[j], 2);
          ep[j] += __shfl_xor(ep[j], 4);
          ep[j] += __shfl_xor(ep[j], 8);
        }
        if ((lane & 15) == 0) {
          #pragma unroll
          for (int j = 0; j < 4; ++j)
            smem[PL_O + rt * 16 + ((lane >> 4) << 2) + j] = ep[j];
        }
      }

      // softmax (own-row read: same wave wrote it)
      const float ee = (tid < len) ? smem[PL_O + tid] : -1e30f;
      float m = ee;
      #pragma unroll
      for (int o = 32; o > 0; o >>= 1) m = fmaxf(m, __shfl_xor(m, o));
      if (lane == 0) smem[RED_O + w] = m;
      __syncthreads();
      if (tid == 0) {
        float mm = smem[RED_O];
        #pragma unroll
        for (int i = 1; i < 8; ++i) mm = fmaxf(mm, smem[RED_O + i]);
        smem[RED_O + 8] = mm;
      }
      __syncthreads();
      const float M = smem[RED_O + 8];
      const float p = (tid < len) ? __expf(ee - M) : 0.f;
      float s = p;
      #pragma unroll
      for (int o = 32; o > 0; o >>= 1) s += __shfl_xor(s, o);
      if (lane == 0) smem[RED_O + w] = s;
      __syncthreads();
      if (tid == 0) {
        float ss = smem[RED_O];
        #pragma unroll
        for (int i = 1; i < 8; ++i) ss += smem[RED_O + i];
        smem[RED_O + 8] = ss;
      }
      __syncthreads();
      const float an = p * (1.f / smem[RED_O + 8]);
      smem[PL_O + tid] = an;
      awcf += an;
      awb[16 + tid] = packh2(an, awcf);
      if (chn == 0) stf32cg(out_align + ((size_t)b * TOUTT + t) * TIN + tid, an);
      __syncthreads();

      // ctx e-quarter (enc16 via nontemporal loads: no L2 pollution)
      {
        const int eo = lane & 15, sub4 = lane >> 4;
        float a8[8];
        #pragma unroll
        for (int i = 0; i < 8; ++i) a8[i] = 0.f;
        const f16* ebase = enc16 + (size_t)(b * TIN) * EEE + chn * 128 + eo * 8;
        #pragma unroll 4
        for (int j = 0; j < 16; ++j) {
          const int tj = w * 64 + sub4 * 16 + j;
          const float wv = smem[PL_O + tj];
          const f16x8 ev = __builtin_nontemporal_load(
              reinterpret_cast<const f16x8*>(ebase + (size_t)tj * EEE));
          #pragma unroll
          for (int i = 0; i < 8; ++i) a8[i] += wv * (float)ev[i];
        }
        #pragma unroll
        for (int i = 0; i < 8; ++i) {
          a8[i] += __shfl_xor(a8[i], 16);
          a8[i] += __shfl_xor(a8[i], 32);
        }
        if (lane < 16) {
          #pragma unroll
          for (int i = 0; i < 8; ++i) smem[PART_O + w * 128 + eo * 8 + i] = a8[i];
        }
      }
      __syncthreads();
      if (tid < 128) {
        float v = 0.f;
        #pragma unroll
        for (int ww = 0; ww < 8; ++ww) v += smem[PART_O + ww * 128 + tid];
        smem[PL_O + tid] = v;
      }
      __syncthreads();
      if (tid < 64) {
        const int ecol = chn * 128 + 2 * tid;
        const unsigned pv = packh2(smem[PL_O + 2 * tid], smem[PL_O + 2 * tid + 1]);
        stu32cg((unsigned*)(xa_h + (size_t)((t + 1) & 1) * 114688 + fragaddr(b, 256 + ecol)), pv);
        stu32cg((unsigned*)(xd_h + (size_t)(t & 1) * 163840 + fragaddr(b, 1024 + ecol)), pv);
        stu32cg((unsigned*)(ctx16 + (size_t)(t & 1) * 32768 + (size_t)b * 512 + ecol), pv);
      }
      if (t > 0 && (chn == 1 || chn == 2))
        do_melgate(b, chn - 1, t - 1, dh16, ctx16 + (size_t)((t - 1) & 1) * 32768,
                   wpjt, bproj, bgate, out_mel, out_gate, smem);
    }
    gbar(bar, syncn, 2);  // B2: acquire-invalidate -> next X's plain frag loads see L3
  }
}

extern "C" void kernel_launch(void* const* d_in, const int* in_sizes, int n_in,
                              void* d_out, int out_size, void* d_ws, size_t ws_size,
                              hipStream_t stream) {
  (void)in_sizes; (void)n_in; (void)out_size; (void)ws_size;
  const float* enc    = (const float*)d_in[0];
  const float* dec_in = (const float*)d_in[1];
  const int*   tlen   = (const int*)d_in[2];
  const float* Wp1    = (const float*)d_in[3];
  const float* Wp2    = (const float*)d_in[4];
  const float* Wi_a   = (const float*)d_in[5];
  const float* Wh_a   = (const float*)d_in[6];
  const float* b_a    = (const float*)d_in[7];
  const float* Wq     = (const float*)d_in[8];
  const float* Wm     = (const float*)d_in[9];
  const float* Wv     = (const float*)d_in[10];
  const float* Kloc   = (const float*)d_in[11];
  const float* Wloc   = (const float*)d_in[12];
  const float* Wi_d   = (const float*)d_in[13];
  const float* Wh_d   = (const float*)d_in[14];
  const float* b_d    = (const float*)d_in[15];
  const float* Wproj  = (const float*)d_in[16];
  const float* bproj  = (const float*)d_in[17];
  const float* Wgate  = (const float*)d_in[18];
  const float* bgate  = (const float*)d_in[19];

  float* ws = (float*)d_ws;
  f16*   wta_h = (f16*)(ws + WTA_OFF);
  f16*   wtd_h = (f16*)(ws + WTD_OFF);
  f16*   pm16  = (f16*)(ws + PM16_OFF);
  f16*   e16   = (f16*)(ws + ENC16_OFF);
  f16*   pre_h = (f16*)(ws + PRE_OFF);
  f16*   xa_h  = (f16*)(ws + XA_OFF);
  f16*   xd_h  = (f16*)(ws + XD_OFF);
  f16*   ah16  = (f16*)(ws + AH16_OFF);
  f16*   dh16  = (f16*)(ws + DH16_OFF);
  f16*   ctx16 = (f16*)(ws + CTX16_OFF);
  f16*   kwb   = (f16*)(ws + EN_OFF);
  f16*   wqt   = (f16*)(ws + WQT_OFF);
  f16*   wpjt  = (f16*)(ws + WPJT_OFF);
  f16*   wp1t  = (f16*)(ws + WP1T_OFF);
  f16*   wp2t  = (f16*)(ws + WP2T_OFF);
  unsigned* bar = (unsigned*)(ws + BAR_OFF);

  float* out_mel   = (float*)d_out;
  float* out_gate  = out_mel + (size_t)BB * NMEL * TOUTT;
  float* out_align = out_gate + (size_t)BB * TOUTT;

  hipMemsetAsync(bar, 0, 272 * sizeof(unsigned), stream);
  transA<<<dim3(28 * 64), dim3(256), 0, stream>>>(Wi_a, Wh_a, wta_h);
  transD<<<dim3(40 * 64), dim3(256), 0, stream>>>(Wi_d, Wh_d, wtd_h);
  pmk<<<dim3(BB * TIN), dim3(128), 0, stream>>>(enc, Wm, pm16);
  enc16k<<<dim3(4096), dim3(512), 0, stream>>>(enc, e16);
  kwk<<<dim3(32), dim3(256), 0, stream>>>(Kloc, Wloc, kwb);
  transAux<<<dim3(667), dim3(512), 0, stream>>>(Wq, Wproj, Wgate, Wp1, Wp2,
                                                wqt, wpjt, wp1t, wp2t);
  prenetk<<<dim3(TOUTT), dim3(512), 0, stream>>>(dec_in, wp1t, wp2t, pre_h);
  decoder_loop<<<dim3(NBLK), dim3(NTHR), 0, stream>>>(
      tlen, b_a, b_d, Wv, bproj, bgate,
      wta_h, wtd_h, pm16, e16, pre_h, wqt, wpjt, kwb,
      xa_h, xd_h, ah16, dh16, ctx16, bar,
      out_mel, out_gate, out_align);
}